// Round 16
// baseline (106.290 us; speedup 1.0000x reference)
//
#include <hip/hip_runtime.h>

#define H_DIM 2048
#define W_DIM 4096
#define ROW4  3072               // float4 per input row

#define G        16              // output rows per block
#define NROW_CAP 20
#define NPX_CAP  272
#define NF4_CAP  204             // (NPX_CAP*3)/4 float4 per staged row
#define NF_CAP   816             // floats per staged row

typedef float fx4 __attribute__((ext_vector_type(4)));
typedef float f3v __attribute__((ext_vector_type(3)));

__device__ __forceinline__ void eval_disp(const float* __restrict__ disp,
                                          int iy, float fyc, int xx,
                                          float& dy, float& dx) {
    float ux = (float)xx * (2.0f / 4095.0f);
    int ix = min((int)ux, 1);
    float fxc = ux - (float)ix;
    const float* dp0 = disp + iy * 3 + ix;
    const float* dp1 = dp0 + 9;
    dy = 5.0f * ((1.0f - fyc) * ((1.0f - fxc) * dp0[0] + fxc * dp0[1])
               +          fyc  * ((1.0f - fxc) * dp0[3] + fxc * dp0[4]));
    dx = 5.0f * ((1.0f - fyc) * ((1.0f - fxc) * dp1[0] + fxc * dp1[1])
               +          fyc  * ((1.0f - fxc) * dp1[3] + fxc * dp1[4]));
}

// ---------------- k0: subsample max (validated R13/R14) -> atomicMax ----------------
__global__ __launch_bounds__(256) void subsample_max_kernel(const float* __restrict__ in,
                                                            unsigned int* __restrict__ ws) {
    const fx4* __restrict__ in4 = (const fx4*)in;
    int base = blockIdx.x * 6144 + threadIdx.x;
    fx4 a = in4[base];
    fx4 b = in4[base + 256];
    float m = fmaxf(fmaxf(fmaxf(a.x, a.y), fmaxf(a.z, a.w)),
                    fmaxf(fmaxf(b.x, b.y), fmaxf(b.z, b.w)));
    #pragma unroll
    for (int off = 32; off > 0; off >>= 1)
        m = fmaxf(m, __shfl_down(m, off, 64));
    __shared__ float smax[4];
    if ((threadIdx.x & 63) == 0) smax[threadIdx.x >> 6] = m;
    __syncthreads();
    if (threadIdx.x == 0)
        atomicMax(ws, __float_as_uint(fmaxf(fmaxf(smax[0], smax[1]), fmaxf(smax[2], smax[3]))));
}

// ---------------- k1: tall-tile staged elastic (cold-capable, coalesced reads) ----------------
// Block = 16 rows x 256 px. Stage rows [ymin..ymin+nrows) x npx cols into LDS (cval in OOB
// slots), then gather 16 px/thread from LDS. Amplification ~1.19x; 2 blocks/CU overlap
// stage(streaming) with gather(LDS).
__global__ __launch_bounds__(256) void elastic_tall_kernel(const float* __restrict__ in,
                                                           const float* __restrict__ disp,
                                                           const unsigned int* __restrict__ ws,
                                                           float* __restrict__ out) {
    __shared__ __align__(16) float stage[NROW_CAP * NF_CAP];   // 65280 B
    const int tid = threadIdx.x;
    const int bid = blockIdx.x;            // 2048 blocks = 128 y-tiles x 16 x-segments
    const int yb  = (bid >> 4) << 4;       // y-tile base (16-row aligned; y-cell aligned)
    const int xs  = (bid & 15) << 8;       // x-segment (256 px; x-cell aligned)
    const int x   = xs + tid;

    const float cval = __uint_as_float(*ws);

    // y-cell uniform across block (1024 % 16 == 0); fyc at top/bottom rows
    float uyT = (float)yb * (2.0f / 2047.0f);
    float uyB = (float)(yb + G - 1) * (2.0f / 2047.0f);
    int iy = min((int)uyT, 1);
    float fycT = uyT - (float)iy;
    float fycB = uyB - (float)iy;

    // corner displacements (disp bilinear within block -> corner extremes bound all pixels)
    float dyTL, dxTL, dyTR, dxTR, dyBL, dxBL, dyBR, dxBR;
    eval_disp(disp, iy, fycT, xs,       dyTL, dxTL);
    eval_disp(disp, iy, fycT, xs + 255, dyTR, dxTR);
    eval_disp(disp, iy, fycB, xs,       dyBL, dxBL);
    eval_disp(disp, iy, fycB, xs + 255, dyBR, dxBR);

    float dyLo = fminf(fminf(dyTL, dyTR), fminf(dyBL, dyBR));
    float dyHi = fmaxf(fmaxf(dyTL, dyTR), fmaxf(dyBL, dyBR));
    float dxLo = fminf(fminf(dxTL, dxTR), fminf(dxBL, dxBR));
    float dxHi = fmaxf(fmaxf(dxTL, dxTR), fmaxf(dxBL, dxBR));

    float cyLo = (float)yb + dyLo;
    float cyHi = (float)(yb + G - 1) + dyHi;
    float cxLo = (float)xs + dxLo;
    float cxHi = (float)(xs + 255) + dxHi;

    int ymin_s = (int)floorf(cyLo);
    int nrows  = (int)floorf(cyHi) - ymin_s + 2;
    int xmin_s = ((int)floorf(cxLo)) & ~3;
    int npx    = (int)floorf(cxHi) + 2 - xmin_s;
    bool fits  = (nrows <= NROW_CAP) && (npx <= NPX_CAP);

    if (fits) {
        // ---- stage: coalesced float4 row-chunks, 3 batches of 8 rows in flight ----
        int nf4v = (npx * 3 + 3) >> 2;          // <= 204
        int gb4  = (xmin_s * 3) >> 2;           // exact: xmin_s multiple of 4
        bool tload = tid < nf4v;
        int c4 = gb4 + tid;
        bool cOOB = (c4 < 0) | (c4 >= ROW4);
        int c4c = min(max(c4, 0), ROW4 - 1);
        fx4 cval4; cval4.x = cval; cval4.y = cval; cval4.z = cval; cval4.w = cval;

        #pragma unroll
        for (int b = 0; b < 3; b++) {
            fx4 tv[8];
            #pragma unroll
            for (int k = 0; k < 8; k++) {
                int r = b * 8 + k;
                if (r < nrows && tload) {
                    int yc = min(max(ymin_s + r, 0), H_DIM - 1);
                    tv[k] = ((const fx4*)in)[yc * ROW4 + c4c];
                }
            }
            #pragma unroll
            for (int k = 0; k < 8; k++) {
                int r = b * 8 + k;
                if (r < nrows && tload) {
                    bool rOOB = ((ymin_s + r) < 0) | ((ymin_s + r) >= H_DIM);
                    fx4 v = (rOOB | cOOB) ? cval4 : tv[k];
                    ((fx4*)stage)[r * NF4_CAP + tid] = v;
                }
            }
        }
        __syncthreads();

        // ---- per-thread disp endpoints at own x; exact linear-in-y interior ----
        float dyT, dxT, dyB2, dxB2;
        eval_disp(disp, iy, fycT, x, dyT, dxT);
        eval_disp(disp, iy, fycB, x, dyB2, dxB2);
        float sdy = (dyB2 - dyT) * (1.0f / (float)(G - 1));
        float sdx = (dxB2 - dxT) * (1.0f / (float)(G - 1));

        // ---- gather 16 rows from LDS (no masks: OOB slots hold cval) ----
        #pragma unroll 4
        for (int r = 0; r < G; r++) {
            float dy = fmaf((float)r, sdy, dyT);
            float dx = fmaf((float)r, sdx, dxT);
            float cy = (float)(yb + r) + dy;
            float cx = (float)x + dx;
            float y0f = floorf(cy);
            float x0f = floorf(cx);
            float fy = cy - y0f;
            float fx = cx - x0f;
            int r0 = min(max((int)y0f - ymin_s, 0), nrows - 2);
            int j0 = min(max((int)x0f - xmin_s, 0), npx - 2);

            const float* p0 = stage + r0 * NF_CAP + j0 * 3;
            const float* p1 = p0 + NF_CAP;

            float g0 = 1.0f - fy, h0 = 1.0f - fx;
            float w00 = g0 * h0, w01 = g0 * fx, w10 = fy * h0, w11 = fy * fx;
            f3v o;
            o.x = fmaf(w00, p0[0], fmaf(w01, p0[3], fmaf(w10, p1[0], w11 * p1[3])));
            o.y = fmaf(w00, p0[1], fmaf(w01, p0[4], fmaf(w10, p1[1], w11 * p1[4])));
            o.z = fmaf(w00, p0[2], fmaf(w01, p0[5], fmaf(w10, p1[2], w11 * p1[5])));

            f3v* dst = (f3v*)(out + ((((yb + r) << 12) + x) * 3));
            __builtin_nontemporal_store(o, dst);
        }
    } else {
        // ---- fallback (pathological disp only): exact per-pixel path ----
        #pragma unroll 1
        for (int r = 0; r < G; r++) {
            int yr = yb + r;
            float uy = (float)yr * (2.0f / 2047.0f);
            float fyc = uy - (float)iy;
            float dy, dx;
            eval_disp(disp, iy, fyc, x, dy, dx);
            float cy = (float)yr + dy;
            float cx = (float)x + dx;
            float y0f = floorf(cy);
            float x0f = floorf(cx);
            float fy = cy - y0f;
            float fx = cx - x0f;
            int y0 = (int)y0f;
            int x0 = (int)x0f;

            int xbase = min(max(x0, 0), W_DIM - 2);
            bool sel = (x0 == xbase);
            bool vx0 = (x0 >= 0) & (x0 <= W_DIM - 1);
            bool vx1 = (x0 >= -1) & (x0 <= W_DIM - 2);
            int yr0 = min(max(y0, 0), H_DIM - 1);
            int yr1 = min(max(y0 + 1, 0), H_DIM - 1);
            bool vy0 = (y0 >= 0) & (y0 < H_DIM);
            bool vy1 = (y0 + 1 >= 0) & (y0 + 1 < H_DIM);

            const float* p0 = in + (((yr0 << 12) + xbase) * 3);
            const float* p1 = in + (((yr1 << 12) + xbase) * 3);
            f3v L00 = *(const f3v*)p0;
            f3v L01 = *(const f3v*)(p0 + 3);
            f3v L10 = *(const f3v*)p1;
            f3v L11 = *(const f3v*)(p1 + 3);

            float g0 = 1.0f - fy, h0 = 1.0f - fx;
            float w00 = g0 * h0, w01 = g0 * fx, w10 = fy * h0, w11 = fy * fx;
            float acc0, acc1, acc2;
            {
                float c0a = sel ? L00.x : L01.x;  float c1a = sel ? L01.x : L00.x;
                float c0b = sel ? L00.y : L01.y;  float c1b = sel ? L01.y : L00.y;
                float c0c = sel ? L00.z : L01.z;  float c1c = sel ? L01.z : L00.z;
                bool v0 = vy0 & vx0, v1 = vy0 & vx1;
                c0a = v0 ? c0a : cval;  c1a = v1 ? c1a : cval;
                c0b = v0 ? c0b : cval;  c1b = v1 ? c1b : cval;
                c0c = v0 ? c0c : cval;  c1c = v1 ? c1c : cval;
                acc0 = fmaf(w00, c0a, w01 * c1a);
                acc1 = fmaf(w00, c0b, w01 * c1b);
                acc2 = fmaf(w00, c0c, w01 * c1c);
            }
            {
                float c0a = sel ? L10.x : L11.x;  float c1a = sel ? L11.x : L10.x;
                float c0b = sel ? L10.y : L11.y;  float c1b = sel ? L11.y : L10.y;
                float c0c = sel ? L10.z : L11.z;  float c1c = sel ? L11.z : L10.z;
                bool v0 = vy1 & vx0, v1 = vy1 & vx1;
                c0a = v0 ? c0a : cval;  c1a = v1 ? c1a : cval;
                c0b = v0 ? c0b : cval;  c1b = v1 ? c1b : cval;
                c0c = v0 ? c0c : cval;  c1c = v1 ? c1c : cval;
                acc0 = fmaf(w10, c0a, fmaf(w11, c1a, acc0));
                acc1 = fmaf(w10, c0b, fmaf(w11, c1b, acc1));
                acc2 = fmaf(w10, c0c, fmaf(w11, c1c, acc2));
            }
            float* o = out + ((((yb + r) << 12) + x) * 3);
            o[0] = acc0;
            o[1] = acc1;
            o[2] = acc2;
        }
    }
}

extern "C" void kernel_launch(void* const* d_in, const int* in_sizes, int n_in,
                              void* d_out, int out_size, void* d_ws, size_t ws_size,
                              hipStream_t stream) {
    const float* in   = (const float*)d_in[0];   // [2048, 4096, 3] f32
    const float* disp = (const float*)d_in[1];   // [2, 3, 3] f32
    float* out = (float*)d_out;
    unsigned int* ws = (unsigned int*)d_ws;

    hipMemsetAsync(d_ws, 0, sizeof(unsigned int), stream);
    subsample_max_kernel<<<64, 256, 0, stream>>>(in, ws);
    elastic_tall_kernel<<<2048, 256, 0, stream>>>(in, disp, ws, out);
}

// Round 17
// 55.936 us; speedup vs baseline: 1.9002x; 1.9002x over previous
//
#include <hip/hip_runtime.h>

#define H_DIM 2048
#define W_DIM 4096

typedef float fx4 __attribute__((ext_vector_type(4)));
typedef float f3v __attribute__((ext_vector_type(3)));

#define WS_PART_OFF 64
#define MAXP_BLOCKS 2048

// ---------------- Pass 1: per-block partial max (no atomics); warms L3 ----------------
// 2048 blocks x 256 thr; 12 float4/thread all in flight. ~16.5us at ~6.1 TB/s.
__global__ __launch_bounds__(256) void max_partial_kernel(const float* __restrict__ in,
                                                          float* __restrict__ wsf) {
    const float4* __restrict__ in4 = (const float4*)in;
    int t = blockIdx.x * 256 + threadIdx.x;
    float4 v[12];
    #pragma unroll
    for (int k = 0; k < 12; k++) v[k] = in4[t + k * (MAXP_BLOCKS * 256)];
    float m = 0.0f;
    #pragma unroll
    for (int k = 0; k < 12; k++)
        m = fmaxf(m, fmaxf(fmaxf(v[k].x, v[k].y), fmaxf(v[k].z, v[k].w)));
    #pragma unroll
    for (int off = 32; off > 0; off >>= 1)
        m = fmaxf(m, __shfl_down(m, off, 64));
    __shared__ float smax[4];
    if ((threadIdx.x & 63) == 0) smax[threadIdx.x >> 6] = m;
    __syncthreads();
    if (threadIdx.x == 0)
        wsf[WS_PART_OFF + blockIdx.x] = fmaxf(fmaxf(smax[0], smax[1]), fmaxf(smax[2], smax[3]));
}

__device__ __forceinline__ void eval_disp(const float* __restrict__ disp,
                                          int iy, float fyc, int xx,
                                          float& dy, float& dx) {
    float ux = (float)xx * (2.0f / 4095.0f);
    int ix = min((int)ux, 1);
    float fxc = ux - (float)ix;
    const float* dp0 = disp + iy * 3 + ix;
    const float* dp1 = dp0 + 9;
    dy = 5.0f * ((1.0f - fyc) * ((1.0f - fxc) * dp0[0] + fxc * dp0[1])
               +          fyc  * ((1.0f - fxc) * dp0[3] + fxc * dp0[4]));
    dx = 5.0f * ((1.0f - fyc) * ((1.0f - fxc) * dp1[0] + fxc * dp1[1])
               +          fyc  * ((1.0f - fxc) * dp1[3] + fxc * dp1[4]));
}

// ---------------- Pass 2: elastic warp (R10 config) + border-side partial reduction ----------
__global__ __launch_bounds__(256) void elastic_sample_kernel(const float* __restrict__ in,
                                                             const float* __restrict__ disp,
                                                             const float* __restrict__ wsf,
                                                             float* __restrict__ out) {
    const int tid = threadIdx.x;
    int bid = blockIdx.x;
    int band = bid & 7;                  // XCD y-band swizzle
    int idx = bid >> 3;
    int y  = (band << 8) + (idx >> 4);
    int xs = (idx & 15) << 8;
    int x  = xs + tid;

    float uy = (float)y * (2.0f / 2047.0f);
    int iy = min((int)uy, 1);
    float fyc = uy - (float)iy;

    // block-uniform endpoint bounds (disp linear in x within the block; cell-aligned)
    float dyA, dxA, dyB, dxB;
    eval_disp(disp, iy, fyc, xs,       dyA, dxA);
    eval_disp(disp, iy, fyc, xs + 255, dyB, dxB);
    float cyLo = (float)y + fminf(dyA, dyB);
    float cyHi = (float)y + fmaxf(dyA, dyB);
    float cxLo = fminf((float)xs + dxA, (float)(xs + 255) + dxB);
    float cxHi = fmaxf((float)xs + dxA, (float)(xs + 255) + dxB);
    bool interior = (cyLo >= 1.0f) & (cyHi <= (float)(H_DIM - 3)) &&
                    (cxLo >= 1.0f) & (cxHi <= (float)(W_DIM - 3));

    float acc0, acc1, acc2;

    if (interior) {
        // ---- fast path: linear disp, no clamps/masks/selects, no LDS/barriers ----
        float sY = (dyB - dyA) * (1.0f / 255.0f);
        float sX = (dxB - dxA) * (1.0f / 255.0f);
        float cy = (float)y + fmaf((float)tid, sY, dyA);
        float cx = (float)x + fmaf((float)tid, sX, dxA);
        float y0f = floorf(cy);
        float x0f = floorf(cx);
        float fy = cy - y0f;
        float fx = cx - x0f;
        int y0 = (int)y0f;
        int x0 = (int)x0f;

        const float* p0 = in + (((y0 << 12) + x0) * 3);
        const float* p1 = p0 + W_DIM * 3;

        f3v L00, L01, L10, L11;
        asm volatile("global_load_dwordx3 %0, %4, off\n\t"
                     "global_load_dwordx3 %1, %4, off offset:12\n\t"
                     "global_load_dwordx3 %2, %5, off\n\t"
                     "global_load_dwordx3 %3, %5, off offset:12"
                     : "=&v"(L00), "=&v"(L01), "=&v"(L10), "=&v"(L11)
                     : "v"(p0), "v"(p1));
        asm volatile("s_waitcnt vmcnt(0)"
                     : "+v"(L00), "+v"(L01), "+v"(L10), "+v"(L11));
        __builtin_amdgcn_sched_barrier(0);

        float g0 = 1.0f - fy, h0 = 1.0f - fx;
        float w00 = g0 * h0, w01 = g0 * fx, w10 = fy * h0, w11 = fy * fx;
        acc0 = fmaf(w00, L00.x, fmaf(w01, L01.x, fmaf(w10, L10.x, w11 * L11.x)));
        acc1 = fmaf(w00, L00.y, fmaf(w01, L01.y, fmaf(w10, L10.y, w11 * L11.y)));
        acc2 = fmaf(w00, L00.z, fmaf(w01, L01.z, fmaf(w10, L10.z, w11 * L11.z)));
    } else {
        // ---- border path: reduce the 2048 partials -> cval (8KB, L2-resident), then exact ----
        const fx4* p4 = (const fx4*)(wsf + WS_PART_OFF);   // 512 fx4
        fx4 pa = p4[tid];
        fx4 pb = p4[tid + 256];
        float mm = fmaxf(fmaxf(fmaxf(pa.x, pa.y), fmaxf(pa.z, pa.w)),
                         fmaxf(fmaxf(pb.x, pb.y), fmaxf(pb.z, pb.w)));
        #pragma unroll
        for (int off = 32; off > 0; off >>= 1)
            mm = fmaxf(mm, __shfl_down(mm, off, 64));
        __shared__ float smax[4];
        if ((tid & 63) == 0) smax[tid >> 6] = mm;
        __syncthreads();
        const float cval = fmaxf(fmaxf(smax[0], smax[1]), fmaxf(smax[2], smax[3]));

        float dy, dx;
        eval_disp(disp, iy, fyc, x, dy, dx);
        float cy = (float)y + dy;
        float cx = (float)x + dx;
        float y0f = floorf(cy);
        float x0f = floorf(cx);
        float fy = cy - y0f;
        float fx = cx - x0f;
        int y0 = (int)y0f;
        int x0 = (int)x0f;

        int xbase = min(max(x0, 0), W_DIM - 2);
        bool sel = (x0 == xbase);
        bool vx0 = (x0 >= 0) & (x0 <= W_DIM - 1);
        bool vx1 = (x0 >= -1) & (x0 <= W_DIM - 2);
        int yr0 = min(max(y0, 0), H_DIM - 1);
        int yr1 = min(max(y0 + 1, 0), H_DIM - 1);
        bool vy0 = (y0 >= 0) & (y0 < H_DIM);
        bool vy1 = (y0 + 1 >= 0) & (y0 + 1 < H_DIM);

        const float* p0 = in + (((yr0 << 12) + xbase) * 3);
        const float* p1 = in + (((yr1 << 12) + xbase) * 3);
        f3v L00 = *(const f3v*)p0;
        f3v L01 = *(const f3v*)(p0 + 3);
        f3v L10 = *(const f3v*)p1;
        f3v L11 = *(const f3v*)(p1 + 3);

        float g0 = 1.0f - fy, h0 = 1.0f - fx;
        float w00 = g0 * h0, w01 = g0 * fx, w10 = fy * h0, w11 = fy * fx;
        {
            float c0a = sel ? L00.x : L01.x;  float c1a = sel ? L01.x : L00.x;
            float c0b = sel ? L00.y : L01.y;  float c1b = sel ? L01.y : L00.y;
            float c0c = sel ? L00.z : L01.z;  float c1c = sel ? L01.z : L00.z;
            bool v0 = vy0 & vx0, v1 = vy0 & vx1;
            c0a = v0 ? c0a : cval;  c1a = v1 ? c1a : cval;
            c0b = v0 ? c0b : cval;  c1b = v1 ? c1b : cval;
            c0c = v0 ? c0c : cval;  c1c = v1 ? c1c : cval;
            acc0 = fmaf(w00, c0a, w01 * c1a);
            acc1 = fmaf(w00, c0b, w01 * c1b);
            acc2 = fmaf(w00, c0c, w01 * c1c);
        }
        {
            float c0a = sel ? L10.x : L11.x;  float c1a = sel ? L11.x : L10.x;
            float c0b = sel ? L10.y : L11.y;  float c1b = sel ? L11.y : L10.y;
            float c0c = sel ? L10.z : L11.z;  float c1c = sel ? L11.z : L10.z;
            bool v0 = vy1 & vx0, v1 = vy1 & vx1;
            c0a = v0 ? c0a : cval;  c1a = v1 ? c1a : cval;
            c0b = v0 ? c0b : cval;  c1b = v1 ? c1b : cval;
            c0c = v0 ? c0c : cval;  c1c = v1 ? c1c : cval;
            acc0 = fmaf(w10, c0a, fmaf(w11, c1a, acc0));
            acc1 = fmaf(w10, c0b, fmaf(w11, c1b, acc1));
            acc2 = fmaf(w10, c0c, fmaf(w11, c1c, acc2));
        }
    }

    // non-temporal 12B store
    f3v r;
    r.x = acc0; r.y = acc1; r.z = acc2;
    f3v* o = (f3v*)(out + (((y << 12) + x) * 3));
    __builtin_nontemporal_store(r, o);
}

extern "C" void kernel_launch(void* const* d_in, const int* in_sizes, int n_in,
                              void* d_out, int out_size, void* d_ws, size_t ws_size,
                              hipStream_t stream) {
    const float* in   = (const float*)d_in[0];   // [2048, 4096, 3] f32
    const float* disp = (const float*)d_in[1];   // [2, 3, 3] f32
    float* out = (float*)d_out;
    float* wsf = (float*)d_ws;

    max_partial_kernel<<<MAXP_BLOCKS, 256, 0, stream>>>(in, wsf);
    elastic_sample_kernel<<<32768, 256, 0, stream>>>(in, disp, wsf, out);
}